// Round 2
// baseline (334.813 us; speedup 1.0000x reference)
//
#include <hip/hip_runtime.h>
#include <math.h>

// CapsuleLayer dynamic routing, fp32, MI355X (gfx950).
// B=64, IN_CAPS=2048, IN_DIM=8, OUT_CAPS=32, OUT_DIM=16, 3 routing iters.
//
// b_ij after r updates = u_hat_i . (v0+...+v_{r-1}) (b starts at 0), so no
// u_hat materialization: each pass recomputes u_hat from W via LDS staging.
//
// R3 -> R4: R3 fixed the LDS pressure (conflicts 0, no staging ds_writes,
// DPP softmax) but dropped occupancy to 1 wave/SIMD (512 blocks x 128 thr =
// 4 waves/CU): VALUBusy 33%, pass 46.6us, latency-bound. R4 doubles the
// grid by halving the i-stripe (IB 8, ISTR 256 -> 1024 blocks = 4 blk/CU =
// 8 waves/CU, the VGPR max at 172 VGPRs; LDS 4x33.8KB fits 160KB). Blocks
// are independent, so barrier drains overlap with other blocks' compute.
// Partials double to 33.5MB; reduce loops 256 stripes (still ~5.5us).

#define IC 2048
#define ID 8
#define OC 32
#define OD 16
#define B_N 64
#define S_ELEMS (B_N * OC * OD)   // 32768
#define IB 8                      // i's per block
#define ISTR (IC / IB)            // 256 i-stripes
#define BPB 16                    // b's per block (8 per wave)
#define BG (B_N / BPB)            // 4 b-groups

// async 16B global->LDS (direct, no VGPR round trip)
__device__ __forceinline__ void gll16(const float4* g, float4* l)
{
    __builtin_amdgcn_global_load_lds(
        (const __attribute__((address_space(1))) void*)g,
        (__attribute__((address_space(3))) void*)l,
        16, 0, 0);
}

// x + dpp_perm(x) on the VALU pipe (no LDS traffic)
template <int CTRL>
__device__ __forceinline__ float dpp_add(float x)
{
    union { float f; int i; } a, b;
    a.f = x;
    b.i = __builtin_amdgcn_update_dpp(0, a.i, CTRL, 0xF, 0xF, true);
    return x + b.f;
}

// W tile i is 1024 float4 "chunks"; global chunk f = (o*16 + j)*2 + dq.
// LDS layout: row o (32 chunks), chunk slot = (j*2+dq) ^ o.  Staging dest is
// linear D = s*128+tid; the matching pre-swizzled source is
//   f(D) = (D>>5)*32 + ((D&31) ^ (D>>5)).
// Hot read, fixed (jj,dq): lanes (o,jh) hit slot ((jh*16+jj*2+dq)^o) in row o
// -> slot%8 uniform over lanes -> conflict-free b128.

template <int FIRST>
__launch_bounds__(128, 2)
__global__ void caps_pass(const float* __restrict__ Wg,
                          const float* __restrict__ xg,
                          const float* __restrict__ vs,
                          float* __restrict__ part)
{
    __shared__ float4 Wl[2][1024];      // 32 KB, double-buffered W tile
    __shared__ float4 xsh[2][BPB * 2];  // 1 KB, x fragments

    const int tid  = threadIdx.x;
    const int lane = tid & 63;
    const int w    = tid >> 6;        // wave 0..1
    const int o    = lane & 31;
    const int jh   = lane >> 5;

    const int is   = blockIdx.x & (ISTR - 1);  // same-W blocks are 256 apart
    const int bg   = blockIdx.x >> 8;          // -> land on the same XCD
    const int bblk = bg * BPB;

    const float4* wq = (const float4*)Wg;

    // v-sum fragments for this wave's 8 b's, held across the i-loop
    float4 va[8], vb[8];
    if (!FIRST) {
#pragma unroll
        for (int n = 0; n < 8; ++n) {
            const float* vp =
                vs + (size_t)(bblk + w * 8 + n) * (OC * OD) + o * OD + jh * 8;
            va[n] = ((const float4*)vp)[0];
            vb[n] = ((const float4*)vp)[1];
        }
    }

    float acc[8][8];
#pragma unroll
    for (int n = 0; n < 8; ++n)
#pragma unroll
        for (int jj = 0; jj < 8; ++jj) acc[n][jj] = 0.0f;

    // ---- prologue: stage tile 0 into parity 0
    {
        const int ig = is * IB;
        const size_t wb0 = (size_t)ig * 1024;
#pragma unroll
        for (int s = 0; s < 8; ++s) {
            const int D = s * 128 + tid;
            const int orow = D >> 5;
            const int f = orow * 32 + ((D & 31) ^ orow);
            gll16(wq + wb0 + f, &Wl[0][D]);
        }
        if (tid < 32)
            xsh[0][tid] = ((const float4*)xg)
                [((size_t)(bblk + (tid >> 1)) * IC + ig) * 2 + (tid & 1)];
    }

    for (int il = 0; il < IB; ++il) {
        const int p = il & 1;
        __syncthreads();   // drains tile(il) loads; nobody reads parity p^1

        // issue next tile's async loads immediately (hide under compute)
        float4 gx = {};
        const bool more = (il + 1 < IB);
        if (more) {
            const int ig = is * IB + il + 1;
            const size_t wb0 = (size_t)ig * 1024;
#pragma unroll
            for (int s = 0; s < 8; ++s) {
                const int D = s * 128 + tid;
                const int orow = D >> 5;
                const int f = orow * 32 + ((D & 31) ^ orow);
                gll16(wq + wb0 + f, &Wl[p ^ 1][D]);
            }
            if (tid < 32)
                gx = ((const float4*)xg)
                    [((size_t)(bblk + (tid >> 1)) * IC + ig) * 2 + (tid & 1)];
        }

        // W fragment -> registers (16 conflict-free ds_read_b128)
        float4 wA[8], wB[8];
        const int row = o * 32;
#pragma unroll
        for (int jj = 0; jj < 8; ++jj) {
            const int ca = (jh * 16 + jj * 2) ^ o;   // dq=0 slot
            wA[jj] = Wl[p][row + ca];
            wB[jj] = Wl[p][row + (ca ^ 1)];          // dq=1 slot
        }

#pragma unroll
        for (int n = 0; n < 8; ++n) {
            const float4 xa = xsh[p][(w * 8 + n) * 2];
            const float4 xb = xsh[p][(w * 8 + n) * 2 + 1];
            float u[8];
#pragma unroll
            for (int jj = 0; jj < 8; ++jj) {
                float t = wA[jj].x * xa.x;
                t = fmaf(wA[jj].y, xa.y, t);
                t = fmaf(wA[jj].z, xa.z, t);
                t = fmaf(wA[jj].w, xa.w, t);
                t = fmaf(wB[jj].x, xb.x, t);
                t = fmaf(wB[jj].y, xb.y, t);
                t = fmaf(wB[jj].z, xb.z, t);
                t = fmaf(wB[jj].w, xb.w, t);
                u[jj] = t;
            }
            float cc;
            if (FIRST) {
                cc = 1.0f;  // softmax(0) = 1/32, folded into the store scale
            } else {
                float bp = u[0] * va[n].x;
                bp = fmaf(u[1], va[n].y, bp);
                bp = fmaf(u[2], va[n].z, bp);
                bp = fmaf(u[3], va[n].w, bp);
                bp = fmaf(u[4], vb[n].x, bp);
                bp = fmaf(u[5], vb[n].y, bp);
                bp = fmaf(u[6], vb[n].z, bp);
                bp = fmaf(u[7], vb[n].w, bp);
                bp += __shfl_xor(bp, 32);            // combine j-halves
                // no max-subtraction: |logit| tiny, exp safe in fp32
                const float e = __expf(bp);
                float t = dpp_add<0xB1>(e);          // quad_perm xor1
                t = dpp_add<0x4E>(t);                // quad_perm xor2
                t = dpp_add<0x124>(t);               // row_ror:4
                t = dpp_add<0x128>(t);               // row_ror:8 -> row sum
                const float se = t + __shfl_xor(t, 16);  // 32-o total
                cc = e * __builtin_amdgcn_rcpf(se);
            }
#pragma unroll
            for (int jj = 0; jj < 8; ++jj)
                acc[n][jj] = fmaf(cc, u[jj], acc[n][jj]);
        }

        // x for next tile (race-free: overwritten parity was last read
        // before the barrier at the top of this iteration)
        if (more && tid < 32) xsh[p ^ 1][tid] = gx;
    }

    // disjoint per-(istripe, b) partials — no atomics, no memset needed
    const float scale = FIRST ? (1.0f / 32.0f) : 1.0f;
#pragma unroll
    for (int n = 0; n < 8; ++n) {
        float* dst = part + (size_t)is * S_ELEMS
                   + (size_t)(bblk + w * 8 + n) * (OC * OD) + o * OD + jh * 8;
        float4 lo = {acc[n][0] * scale, acc[n][1] * scale,
                     acc[n][2] * scale, acc[n][3] * scale};
        float4 hi = {acc[n][4] * scale, acc[n][5] * scale,
                     acc[n][6] * scale, acc[n][7] * scale};
        ((float4*)dst)[0] = lo;
        ((float4*)dst)[1] = hi;
    }
}

// Fused 256-way partial reduction + squash, 512 blocks (2/CU).
// Block handles 64 elems; wave w sums stripes k===w (mod 4), coalesced 256B
// wave-loads; 4-way LDS combine; squash over 16-j lane groups.
// MODE 0: vsum = v   MODE 1: vsum += v   MODE 2: out = v
template <int MODE>
__launch_bounds__(256, 4)
__global__ void caps_reduce(const float* __restrict__ part,
                            float* __restrict__ vsum,
                            float* __restrict__ out)
{
    __shared__ float red[4][64];
    const int tid  = threadIdx.x;
    const int w    = tid >> 6;
    const int lane = tid & 63;
    const int e0   = blockIdx.x * 64;

    float s = 0.0f;
#pragma unroll 8
    for (int k = w; k < ISTR; k += 4)
        s += part[(size_t)k * S_ELEMS + e0 + lane];
    red[w][lane] = s;
    __syncthreads();

    if (tid < 64) {
        const float t = red[0][tid] + red[1][tid] + red[2][tid] + red[3][tid];
        float s2 = t * t;               // ||s||^2 over the 16 j's
        s2 += __shfl_xor(s2, 1);
        s2 += __shfl_xor(s2, 2);
        s2 += __shfl_xor(s2, 4);
        s2 += __shfl_xor(s2, 8);
        const float v = t * (s2 / ((1.0f + s2) * sqrtf(s2 + 1e-9f)));
        const int e = e0 + tid;
        if (MODE == 0)      vsum[e] = v;
        else if (MODE == 1) vsum[e] += v;
        else                out[e] = v;
    }
}

extern "C" void kernel_launch(void* const* d_in, const int* in_sizes, int n_in,
                              void* d_out, int out_size, void* d_ws, size_t ws_size,
                              hipStream_t stream)
{
    const float* x = (const float*)d_in[0];   // [64, 2048, 8]
    const float* W = (const float*)d_in[1];   // [1, 2048, 32, 16, 8]
    float* out = (float*)d_out;               // [64, 32, 16]

    float* part = (float*)d_ws;                        // 256 x 32768 = 33.5 MB
    float* vsum = part + (size_t)ISTR * S_ELEMS;       // 32768 floats

    const dim3 gP(BG * ISTR);     // 1024 blocks
    const dim3 bP(128);
    const dim3 gR(S_ELEMS / 64);  // 512 blocks
    const dim3 bR(256);

    // round 0: c uniform
    caps_pass<1><<<gP, bP, 0, stream>>>(W, x, nullptr, part);
    caps_reduce<0><<<gR, bR, 0, stream>>>(part, vsum, out);   // vsum = v0
    // round 1: b = u.v0
    caps_pass<0><<<gP, bP, 0, stream>>>(W, x, vsum, part);
    caps_reduce<1><<<gR, bR, 0, stream>>>(part, vsum, out);   // vsum = v0+v1
    // round 2: b = u.(v0+v1)
    caps_pass<0><<<gP, bP, 0, stream>>>(W, x, vsum, part);
    caps_reduce<2><<<gR, bR, 0, stream>>>(part, vsum, out);   // out = v2
}

// Round 3
// 216.558 us; speedup vs baseline: 1.5461x; 1.5461x over previous
//
#include <hip/hip_runtime.h>
#include <math.h>

// CapsuleLayer dynamic routing, fp32, MI355X (gfx950).
// B=64, IN_CAPS=2048, IN_DIM=8, OUT_CAPS=32, OUT_DIM=16, 3 routing iters.
//
// b_ij after r updates = u_hat_i . (v0+...+v_{r-1}) (b starts at 0), so no
// u_hat materialization: each pass recomputes u_hat from W via LDS staging.
//
// R4 -> R5: R4's __launch_bounds__(128,2) capped VGPRs at 128 vs ~192 live
// floats -> scratch spills (FETCH 132MB, WRITE 76MB, VALUBusy 13%) that also
// thrashed L3 so W stopped caching. R5 reverts to (128,1): ~172 VGPR, no
// spill. Occupancy target is met by the GRID instead: IB=8 -> 1024 blocks =
// 4 blk/CU x 2 waves = 8 waves/CU = 2 waves/SIMD (172*2=344 <= 512 VGPR/SIMD,
// 4x33.8KB = 135KB <= 160KB LDS). R3's single deficiency was 512 blocks = 4
// waves/CU (grid-limited, NOT VGPR-limited as R4 assumed).

#define IC 2048
#define ID 8
#define OC 32
#define OD 16
#define B_N 64
#define S_ELEMS (B_N * OC * OD)   // 32768
#define IB 8                      // i's per block
#define ISTR (IC / IB)            // 256 i-stripes
#define BPB 16                    // b's per block (8 per wave)
#define BG (B_N / BPB)            // 4 b-groups

// async 16B global->LDS (direct, no VGPR round trip)
__device__ __forceinline__ void gll16(const float4* g, float4* l)
{
    __builtin_amdgcn_global_load_lds(
        (const __attribute__((address_space(1))) void*)g,
        (__attribute__((address_space(3))) void*)l,
        16, 0, 0);
}

// x + dpp_perm(x) on the VALU pipe (no LDS traffic)
template <int CTRL>
__device__ __forceinline__ float dpp_add(float x)
{
    union { float f; int i; } a, b;
    a.f = x;
    b.i = __builtin_amdgcn_update_dpp(0, a.i, CTRL, 0xF, 0xF, true);
    return x + b.f;
}

// W tile i is 1024 float4 "chunks"; global chunk f = (o*16 + j)*2 + dq.
// LDS layout: row o (32 chunks), chunk slot = (j*2+dq) ^ o.  Staging dest is
// linear D = s*128+tid; the matching pre-swizzled source is
//   f(D) = (D>>5)*32 + ((D&31) ^ (D>>5)).
// Hot read, fixed (jj,dq): lanes (o,jh) hit slot ((jh*16+jj*2+dq)^o) in row o
// -> slot%8 uniform over lanes -> conflict-free b128.

template <int FIRST>
__launch_bounds__(128, 1)
__global__ void caps_pass(const float* __restrict__ Wg,
                          const float* __restrict__ xg,
                          const float* __restrict__ vs,
                          float* __restrict__ part)
{
    __shared__ float4 Wl[2][1024];      // 32 KB, double-buffered W tile
    __shared__ float4 xsh[2][BPB * 2];  // 1 KB, x fragments

    const int tid  = threadIdx.x;
    const int lane = tid & 63;
    const int w    = tid >> 6;        // wave 0..1
    const int o    = lane & 31;
    const int jh   = lane >> 5;

    const int is   = blockIdx.x & (ISTR - 1);  // same-W blocks are 256 apart
    const int bg   = blockIdx.x >> 8;          // -> land on the same XCD
    const int bblk = bg * BPB;

    const float4* wq = (const float4*)Wg;

    // v-sum fragments for this wave's 8 b's, held across the i-loop
    float4 va[8], vb[8];
    if (!FIRST) {
#pragma unroll
        for (int n = 0; n < 8; ++n) {
            const float* vp =
                vs + (size_t)(bblk + w * 8 + n) * (OC * OD) + o * OD + jh * 8;
            va[n] = ((const float4*)vp)[0];
            vb[n] = ((const float4*)vp)[1];
        }
    }

    float acc[8][8];
#pragma unroll
    for (int n = 0; n < 8; ++n)
#pragma unroll
        for (int jj = 0; jj < 8; ++jj) acc[n][jj] = 0.0f;

    // ---- prologue: stage tile 0 into parity 0
    {
        const int ig = is * IB;
        const size_t wb0 = (size_t)ig * 1024;
#pragma unroll
        for (int s = 0; s < 8; ++s) {
            const int D = s * 128 + tid;
            const int orow = D >> 5;
            const int f = orow * 32 + ((D & 31) ^ orow);
            gll16(wq + wb0 + f, &Wl[0][D]);
        }
        if (tid < 32)
            xsh[0][tid] = ((const float4*)xg)
                [((size_t)(bblk + (tid >> 1)) * IC + ig) * 2 + (tid & 1)];
    }

    for (int il = 0; il < IB; ++il) {
        const int p = il & 1;
        __syncthreads();   // drains tile(il) loads; nobody reads parity p^1

        // issue next tile's async loads immediately (hide under compute)
        float4 gx = {};
        const bool more = (il + 1 < IB);
        if (more) {
            const int ig = is * IB + il + 1;
            const size_t wb0 = (size_t)ig * 1024;
#pragma unroll
            for (int s = 0; s < 8; ++s) {
                const int D = s * 128 + tid;
                const int orow = D >> 5;
                const int f = orow * 32 + ((D & 31) ^ orow);
                gll16(wq + wb0 + f, &Wl[p ^ 1][D]);
            }
            if (tid < 32)
                gx = ((const float4*)xg)
                    [((size_t)(bblk + (tid >> 1)) * IC + ig) * 2 + (tid & 1)];
        }

        // W fragment -> registers (16 conflict-free ds_read_b128)
        float4 wA[8], wB[8];
        const int row = o * 32;
#pragma unroll
        for (int jj = 0; jj < 8; ++jj) {
            const int ca = (jh * 16 + jj * 2) ^ o;   // dq=0 slot
            wA[jj] = Wl[p][row + ca];
            wB[jj] = Wl[p][row + (ca ^ 1)];          // dq=1 slot
        }

#pragma unroll
        for (int n = 0; n < 8; ++n) {
            const float4 xa = xsh[p][(w * 8 + n) * 2];
            const float4 xb = xsh[p][(w * 8 + n) * 2 + 1];
            float u[8];
#pragma unroll
            for (int jj = 0; jj < 8; ++jj) {
                float t = wA[jj].x * xa.x;
                t = fmaf(wA[jj].y, xa.y, t);
                t = fmaf(wA[jj].z, xa.z, t);
                t = fmaf(wA[jj].w, xa.w, t);
                t = fmaf(wB[jj].x, xb.x, t);
                t = fmaf(wB[jj].y, xb.y, t);
                t = fmaf(wB[jj].z, xb.z, t);
                t = fmaf(wB[jj].w, xb.w, t);
                u[jj] = t;
            }
            float cc;
            if (FIRST) {
                cc = 1.0f;  // softmax(0) = 1/32, folded into the store scale
            } else {
                float bp = u[0] * va[n].x;
                bp = fmaf(u[1], va[n].y, bp);
                bp = fmaf(u[2], va[n].z, bp);
                bp = fmaf(u[3], va[n].w, bp);
                bp = fmaf(u[4], vb[n].x, bp);
                bp = fmaf(u[5], vb[n].y, bp);
                bp = fmaf(u[6], vb[n].z, bp);
                bp = fmaf(u[7], vb[n].w, bp);
                bp += __shfl_xor(bp, 32);            // combine j-halves
                // no max-subtraction: |logit| tiny, exp safe in fp32
                const float e = __expf(bp);
                float t = dpp_add<0xB1>(e);          // quad_perm xor1
                t = dpp_add<0x4E>(t);                // quad_perm xor2
                t = dpp_add<0x124>(t);               // row_ror:4
                t = dpp_add<0x128>(t);               // row_ror:8 -> row sum
                const float se = t + __shfl_xor(t, 16);  // 32-o total
                cc = e * __builtin_amdgcn_rcpf(se);
            }
#pragma unroll
            for (int jj = 0; jj < 8; ++jj)
                acc[n][jj] = fmaf(cc, u[jj], acc[n][jj]);
        }

        // x for next tile (race-free: overwritten parity was last read
        // before the barrier at the top of this iteration)
        if (more && tid < 32) xsh[p ^ 1][tid] = gx;
    }

    // disjoint per-(istripe, b) partials — no atomics, no memset needed
    const float scale = FIRST ? (1.0f / 32.0f) : 1.0f;
#pragma unroll
    for (int n = 0; n < 8; ++n) {
        float* dst = part + (size_t)is * S_ELEMS
                   + (size_t)(bblk + w * 8 + n) * (OC * OD) + o * OD + jh * 8;
        float4 lo = {acc[n][0] * scale, acc[n][1] * scale,
                     acc[n][2] * scale, acc[n][3] * scale};
        float4 hi = {acc[n][4] * scale, acc[n][5] * scale,
                     acc[n][6] * scale, acc[n][7] * scale};
        ((float4*)dst)[0] = lo;
        ((float4*)dst)[1] = hi;
    }
}

// Fused 256-way partial reduction + squash, 512 blocks (2/CU).
// Block handles 64 elems; wave w sums stripes k===w (mod 4), coalesced 256B
// wave-loads; 4-way LDS combine; squash over 16-j lane groups.
// MODE 0: vsum = v   MODE 1: vsum += v   MODE 2: out = v
template <int MODE>
__launch_bounds__(256, 4)
__global__ void caps_reduce(const float* __restrict__ part,
                            float* __restrict__ vsum,
                            float* __restrict__ out)
{
    __shared__ float red[4][64];
    const int tid  = threadIdx.x;
    const int w    = tid >> 6;
    const int lane = tid & 63;
    const int e0   = blockIdx.x * 64;

    float s = 0.0f;
#pragma unroll 8
    for (int k = w; k < ISTR; k += 4)
        s += part[(size_t)k * S_ELEMS + e0 + lane];
    red[w][lane] = s;
    __syncthreads();

    if (tid < 64) {
        const float t = red[0][tid] + red[1][tid] + red[2][tid] + red[3][tid];
        float s2 = t * t;               // ||s||^2 over the 16 j's
        s2 += __shfl_xor(s2, 1);
        s2 += __shfl_xor(s2, 2);
        s2 += __shfl_xor(s2, 4);
        s2 += __shfl_xor(s2, 8);
        const float v = t * (s2 / ((1.0f + s2) * sqrtf(s2 + 1e-9f)));
        const int e = e0 + tid;
        if (MODE == 0)      vsum[e] = v;
        else if (MODE == 1) vsum[e] += v;
        else                out[e] = v;
    }
}

extern "C" void kernel_launch(void* const* d_in, const int* in_sizes, int n_in,
                              void* d_out, int out_size, void* d_ws, size_t ws_size,
                              hipStream_t stream)
{
    const float* x = (const float*)d_in[0];   // [64, 2048, 8]
    const float* W = (const float*)d_in[1];   // [1, 2048, 32, 16, 8]
    float* out = (float*)d_out;               // [64, 32, 16]

    float* part = (float*)d_ws;                        // 256 x 32768 = 33.5 MB
    float* vsum = part + (size_t)ISTR * S_ELEMS;       // 32768 floats

    const dim3 gP(BG * ISTR);     // 1024 blocks
    const dim3 bP(128);
    const dim3 gR(S_ELEMS / 64);  // 512 blocks
    const dim3 bR(256);

    // round 0: c uniform
    caps_pass<1><<<gP, bP, 0, stream>>>(W, x, nullptr, part);
    caps_reduce<0><<<gR, bR, 0, stream>>>(part, vsum, out);   // vsum = v0
    // round 1: b = u.v0
    caps_pass<0><<<gP, bP, 0, stream>>>(W, x, vsum, part);
    caps_reduce<1><<<gR, bR, 0, stream>>>(part, vsum, out);   // vsum = v0+v1
    // round 2: b = u.(v0+v1)
    caps_pass<0><<<gP, bP, 0, stream>>>(W, x, vsum, part);
    caps_reduce<2><<<gR, bR, 0, stream>>>(part, vsum, out);   // out = v2
}

// Round 4
// 169.761 us; speedup vs baseline: 1.9723x; 1.2757x over previous
//
#include <hip/hip_runtime.h>
#include <math.h>

// CapsuleLayer dynamic routing, fp32, MI355X (gfx950).
// B=64, IN_CAPS=2048, IN_DIM=8, OUT_CAPS=32, OUT_DIM=16, 3 routing iters.
//
// b_ij after r updates = u_hat_i . (v0+...+v_{r-1}) (b starts at 0), so no
// u_hat materialization: each pass recomputes u_hat from W via LDS staging.
//
// R5 -> R6: R5 proved the binder is wave supply, not LDS ops: 128-thread
// 2-wave blocks never exceeded ~3-4 waves/CU (VALUBusy 31%) regardless of
// grid size, while R2's 256-thread 4-wave shape (grid 512 = 2 blk/CU x 4
// waves = 8 waves/CU) was empirically fastest overall. R6 = R2's shape +
// R3/R5's local wins kept: global_load_lds W staging (no ds_writes, no
// staging VGPRs), XOR-swizzle conflict-free W ds_read_b128, DPP softmax
// (2 LDS shuffle ops per n instead of 6), 512-block fused reduce.
// Each wave owns 4 b's; all 4 waves read the shared 16KB W tile from LDS.

#define IC 2048
#define ID 8
#define OC 32
#define OD 16
#define B_N 64
#define S_ELEMS (B_N * OC * OD)   // 32768
#define IB 16                     // i's per block
#define ISTR (IC / IB)            // 128 i-stripes
#define BPB 16                    // b's per block (4 per wave)
#define BG (B_N / BPB)            // 4 b-groups

// async 16B global->LDS (direct, no VGPR round trip)
__device__ __forceinline__ void gll16(const float4* g, float4* l)
{
    __builtin_amdgcn_global_load_lds(
        (const __attribute__((address_space(1))) void*)g,
        (__attribute__((address_space(3))) void*)l,
        16, 0, 0);
}

// x + dpp_perm(x) on the VALU pipe (no LDS traffic)
template <int CTRL>
__device__ __forceinline__ float dpp_add(float x)
{
    union { float f; int i; } a, b;
    a.f = x;
    b.i = __builtin_amdgcn_update_dpp(0, a.i, CTRL, 0xF, 0xF, true);
    return x + b.f;
}

// W tile i is 1024 float4 "chunks"; global chunk f = (o*16 + j)*2 + dq.
// LDS layout: row o (32 chunks), chunk slot = (j*2+dq) ^ o.  Staging dest is
// linear D = s*256+tid; the matching pre-swizzled source is
//   f(D) = (D>>5)*32 + ((D&31) ^ (D>>5)).
// Hot read, fixed (jj,dq): lanes (o,jh) hit slot ((jh*16+jj*2+dq)^o) in row o
// -> slot%8 uniform over lanes -> conflict-free b128.

template <int FIRST>
__launch_bounds__(256, 2)
__global__ void caps_pass(const float* __restrict__ Wg,
                          const float* __restrict__ xg,
                          const float* __restrict__ vs,
                          float* __restrict__ part)
{
    __shared__ float4 Wl[2][1024];      // 32 KB, double-buffered W tile
    __shared__ float4 xsh[2][BPB * 2];  // 1 KB, x fragments

    const int tid  = threadIdx.x;
    const int lane = tid & 63;
    const int w    = tid >> 6;        // wave 0..3
    const int o    = lane & 31;
    const int jh   = lane >> 5;

    const int is   = blockIdx.x & (ISTR - 1);  // same-W blocks are 128 apart
    const int bg   = blockIdx.x >> 7;          // -> land on the same XCD
    const int bblk = bg * BPB;

    const float4* wq = (const float4*)Wg;

    // v-sum fragments for this wave's 4 b's, held across the i-loop
    float4 va[4], vb[4];
    if (!FIRST) {
#pragma unroll
        for (int n = 0; n < 4; ++n) {
            const float* vp =
                vs + (size_t)(bblk + w * 4 + n) * (OC * OD) + o * OD + jh * 8;
            va[n] = ((const float4*)vp)[0];
            vb[n] = ((const float4*)vp)[1];
        }
    }

    float acc[4][8];
#pragma unroll
    for (int n = 0; n < 4; ++n)
#pragma unroll
        for (int jj = 0; jj < 8; ++jj) acc[n][jj] = 0.0f;

    // ---- prologue: stage tile 0 into parity 0
    {
        const int ig = is * IB;
        const size_t wb0 = (size_t)ig * 1024;
#pragma unroll
        for (int s = 0; s < 4; ++s) {
            const int D = s * 256 + tid;
            const int orow = D >> 5;
            const int f = orow * 32 + ((D & 31) ^ orow);
            gll16(wq + wb0 + f, &Wl[0][D]);
        }
        if (tid < 32)
            xsh[0][tid] = ((const float4*)xg)
                [((size_t)(bblk + (tid >> 1)) * IC + ig) * 2 + (tid & 1)];
    }

    for (int il = 0; il < IB; ++il) {
        const int p = il & 1;
        __syncthreads();   // drains tile(il) loads; nobody reads parity p^1

        // issue next tile's async loads immediately (hide under compute)
        float4 gx = {};
        const bool more = (il + 1 < IB);
        if (more) {
            const int ig = is * IB + il + 1;
            const size_t wb0 = (size_t)ig * 1024;
#pragma unroll
            for (int s = 0; s < 4; ++s) {
                const int D = s * 256 + tid;
                const int orow = D >> 5;
                const int f = orow * 32 + ((D & 31) ^ orow);
                gll16(wq + wb0 + f, &Wl[p ^ 1][D]);
            }
            if (tid < 32)
                gx = ((const float4*)xg)
                    [((size_t)(bblk + (tid >> 1)) * IC + ig) * 2 + (tid & 1)];
        }

        // W fragment -> registers (16 conflict-free ds_read_b128)
        float4 wA[8], wB[8];
        const int row = o * 32;
#pragma unroll
        for (int jj = 0; jj < 8; ++jj) {
            const int ca = (jh * 16 + jj * 2) ^ o;   // dq=0 slot
            wA[jj] = Wl[p][row + ca];
            wB[jj] = Wl[p][row + (ca ^ 1)];          // dq=1 slot
        }

#pragma unroll
        for (int n = 0; n < 4; ++n) {
            const float4 xa = xsh[p][(w * 4 + n) * 2];
            const float4 xb = xsh[p][(w * 4 + n) * 2 + 1];
            float u[8];
#pragma unroll
            for (int jj = 0; jj < 8; ++jj) {
                float t = wA[jj].x * xa.x;
                t = fmaf(wA[jj].y, xa.y, t);
                t = fmaf(wA[jj].z, xa.z, t);
                t = fmaf(wA[jj].w, xa.w, t);
                t = fmaf(wB[jj].x, xb.x, t);
                t = fmaf(wB[jj].y, xb.y, t);
                t = fmaf(wB[jj].z, xb.z, t);
                t = fmaf(wB[jj].w, xb.w, t);
                u[jj] = t;
            }
            float cc;
            if (FIRST) {
                cc = 1.0f;  // softmax(0) = 1/32, folded into the store scale
            } else {
                float bp = u[0] * va[n].x;
                bp = fmaf(u[1], va[n].y, bp);
                bp = fmaf(u[2], va[n].z, bp);
                bp = fmaf(u[3], va[n].w, bp);
                bp = fmaf(u[4], vb[n].x, bp);
                bp = fmaf(u[5], vb[n].y, bp);
                bp = fmaf(u[6], vb[n].z, bp);
                bp = fmaf(u[7], vb[n].w, bp);
                bp += __shfl_xor(bp, 32);            // combine j-halves
                // no max-subtraction: |logit| tiny, exp safe in fp32
                const float e = __expf(bp);
                float t = dpp_add<0xB1>(e);          // quad_perm xor1
                t = dpp_add<0x4E>(t);                // quad_perm xor2
                t = dpp_add<0x124>(t);               // row_ror:4
                t = dpp_add<0x128>(t);               // row_ror:8 -> row sum
                const float se = t + __shfl_xor(t, 16);  // 32-o total
                cc = e * __builtin_amdgcn_rcpf(se);
            }
#pragma unroll
            for (int jj = 0; jj < 8; ++jj)
                acc[n][jj] = fmaf(cc, u[jj], acc[n][jj]);
        }

        // x for next tile (race-free: overwritten parity was last read
        // before the barrier at the top of this iteration)
        if (more && tid < 32) xsh[p ^ 1][tid] = gx;
    }

    // disjoint per-(istripe, b) partials — no atomics, no memset needed
    const float scale = FIRST ? (1.0f / 32.0f) : 1.0f;
#pragma unroll
    for (int n = 0; n < 4; ++n) {
        float* dst = part + (size_t)is * S_ELEMS
                   + (size_t)(bblk + w * 4 + n) * (OC * OD) + o * OD + jh * 8;
        float4 lo = {acc[n][0] * scale, acc[n][1] * scale,
                     acc[n][2] * scale, acc[n][3] * scale};
        float4 hi = {acc[n][4] * scale, acc[n][5] * scale,
                     acc[n][6] * scale, acc[n][7] * scale};
        ((float4*)dst)[0] = lo;
        ((float4*)dst)[1] = hi;
    }
}

// Fused 128-way partial reduction + squash, 512 blocks (2/CU).
// Block handles 64 elems; wave w sums stripes k===w (mod 4), coalesced 256B
// wave-loads; 4-way LDS combine; squash over 16-j lane groups.
// MODE 0: vsum = v   MODE 1: vsum += v   MODE 2: out = v
template <int MODE>
__launch_bounds__(256, 4)
__global__ void caps_reduce(const float* __restrict__ part,
                            float* __restrict__ vsum,
                            float* __restrict__ out)
{
    __shared__ float red[4][64];
    const int tid  = threadIdx.x;
    const int w    = tid >> 6;
    const int lane = tid & 63;
    const int e0   = blockIdx.x * 64;

    float s = 0.0f;
#pragma unroll 8
    for (int k = w; k < ISTR; k += 4)
        s += part[(size_t)k * S_ELEMS + e0 + lane];
    red[w][lane] = s;
    __syncthreads();

    if (tid < 64) {
        const float t = red[0][tid] + red[1][tid] + red[2][tid] + red[3][tid];
        float s2 = t * t;               // ||s||^2 over the 16 j's
        s2 += __shfl_xor(s2, 1);
        s2 += __shfl_xor(s2, 2);
        s2 += __shfl_xor(s2, 4);
        s2 += __shfl_xor(s2, 8);
        const float v = t * (s2 / ((1.0f + s2) * sqrtf(s2 + 1e-9f)));
        const int e = e0 + tid;
        if (MODE == 0)      vsum[e] = v;
        else if (MODE == 1) vsum[e] += v;
        else                out[e] = v;
    }
}

extern "C" void kernel_launch(void* const* d_in, const int* in_sizes, int n_in,
                              void* d_out, int out_size, void* d_ws, size_t ws_size,
                              hipStream_t stream)
{
    const float* x = (const float*)d_in[0];   // [64, 2048, 8]
    const float* W = (const float*)d_in[1];   // [1, 2048, 32, 16, 8]
    float* out = (float*)d_out;               // [64, 32, 16]

    float* part = (float*)d_ws;                        // 128 x 32768 = 16.8 MB
    float* vsum = part + (size_t)ISTR * S_ELEMS;       // 32768 floats

    const dim3 gP(BG * ISTR);     // 512 blocks
    const dim3 bP(256);
    const dim3 gR(S_ELEMS / 64);  // 512 blocks
    const dim3 bR(256);

    // round 0: c uniform
    caps_pass<1><<<gP, bP, 0, stream>>>(W, x, nullptr, part);
    caps_reduce<0><<<gR, bR, 0, stream>>>(part, vsum, out);   // vsum = v0
    // round 1: b = u.v0
    caps_pass<0><<<gP, bP, 0, stream>>>(W, x, vsum, part);
    caps_reduce<1><<<gR, bR, 0, stream>>>(part, vsum, out);   // vsum = v0+v1
    // round 2: b = u.(v0+v1)
    caps_pass<0><<<gP, bP, 0, stream>>>(W, x, vsum, part);
    caps_reduce<2><<<gR, bR, 0, stream>>>(part, vsum, out);   // out = v2
}